// Round 10
// baseline (614.230 us; speedup 1.0000x reference)
//
#include <hip/hip_runtime.h>
#include <hip/hip_bf16.h>
#include <cstddef>

#define B_   4
#define L_   2048
#define DM   1024
#define DI   2048
#define NST  16
#define DTR  64        // (1024+15)//16 = 64
#define NBC  96        // DTR + 2*NST
#define NTOK 8192      // B_*L_

using bf16 = __hip_bfloat16;
typedef __attribute__((ext_vector_type(8))) short bf16x8;
typedef __attribute__((ext_vector_type(4))) short s16x4;
typedef __attribute__((ext_vector_type(4))) float f32x4;

__device__ __forceinline__ float bf2f(short s) {
  unsigned u = ((unsigned)(unsigned short)s) << 16;
  float f; __builtin_memcpy(&f, &u, 4); return f;
}
__device__ __forceinline__ short f2bs(float f) {
  __hip_bfloat16 h = __float2bfloat16(f);
  short s; __builtin_memcpy(&s, &h, 2); return s;
}
__device__ __forceinline__ float sigmoidf_fast(float x) {
  return 1.f / (1.f + __expf(-x));
}

// async global->LDS, 16B per lane (dest must be wave-uniform base + lane*16)
#define GLD16(g, l) __builtin_amdgcn_global_load_lds( \
  (const __attribute__((address_space(1))) unsigned int*)(g), \
  (__attribute__((address_space(3))) unsigned int*)(l), 16, 0, 0)

// cross-lane xor shuffles for the 16-state butterfly reduce (within 32-lane halves)
__device__ __forceinline__ float swz_xor8(float x) {
  return __builtin_bit_cast(float,
    __builtin_amdgcn_ds_swizzle(__builtin_bit_cast(int, x), 0x201F)); // lane ^= 8
}
__device__ __forceinline__ float swz_xor4(float x) {
  return __builtin_bit_cast(float,
    __builtin_amdgcn_ds_swizzle(__builtin_bit_cast(int, x), 0x101F)); // lane ^= 4
}
template<int CTRL>
__device__ __forceinline__ float qperm(float x) {  // DPP quad_perm, full VALU rate
  return __builtin_bit_cast(float,
    __builtin_amdgcn_update_dpp(0, __builtin_bit_cast(int, x), CTRL, 0xf, 0xf, false));
}
// broadcast lane (group_base | S) to all 16 lanes of the group
template<int S>
__device__ __forceinline__ float swz_bcast16(float x) {
  return __builtin_bit_cast(float,
    __builtin_amdgcn_ds_swizzle(__builtin_bit_cast(int, x), (S << 5) | 0x10));
}

// ---------------------------------------------------------------------------
// shared transpose tile helper (f32 -> bf16, zero-pad)
// ---------------------------------------------------------------------------
__device__ __forceinline__ void transpose_tile(
    const float* __restrict__ in, short* __restrict__ out,
    int R, int Cc, int lin, int lout, int bx, int by, int tid, short (*t)[33])
{
  const int r0 = bx * 32, c0 = by * 32;
  const int tx = tid & 31, ty = tid >> 5;
#pragma unroll
  for (int i = 0; i < 4; i++) {
    int r = r0 + ty + i * 8;
    int c = c0 + tx;
    short v = 0;
    if (r < R && c < Cc) v = f2bs(in[(size_t)r * lin + c]);
    t[ty + i * 8][tx] = v;
  }
  __syncthreads();
#pragma unroll
  for (int i = 0; i < 4; i++) {
    int c = c0 + ty + i * 8;
    int r = r0 + tx;
    if (c < Cc && r < lout) out[(size_t)c * lout + r] = t[tx][ty + i * 8];
  }
}

// ---------------------------------------------------------------------------
// prep: one dispatch doing (a) u f32->bf16 convert, (b) in_proj^T,
// (c) x_proj^T, (d) dt_proj^T.  Linear block id -> region.
// ---------------------------------------------------------------------------
__global__ __launch_bounds__(256)
void prep(const float* __restrict__ u, short* __restrict__ ub,
          const float* __restrict__ in_proj, short* __restrict__ Wt1,
          const float* __restrict__ x_proj, short* __restrict__ Wxp,
          const float* __restrict__ dt_proj, short* __restrict__ dtw)
{
  __shared__ short t[32][33];
  int id = blockIdx.x;
  const int tid = threadIdx.x;
  if (id < 4096) {                       // u convert: 4096 blocks x 256 thr x 8
    const size_t i = ((size_t)id * 256 + tid) * 8;
    float4 a0 = *(const float4*)(u + i);
    float4 a1 = *(const float4*)(u + i + 4);
    union { bf16x8 v; short h[8]; } o;
    o.h[0] = f2bs(a0.x); o.h[1] = f2bs(a0.y); o.h[2] = f2bs(a0.z); o.h[3] = f2bs(a0.w);
    o.h[4] = f2bs(a1.x); o.h[5] = f2bs(a1.y); o.h[6] = f2bs(a1.z); o.h[7] = f2bs(a1.w);
    *(bf16x8*)(ub + i) = o.v;
    return;
  }
  id -= 4096;
  if (id < 4096) {                       // in_proj^T: grid (32,128)
    transpose_tile(in_proj, Wt1, 1024, 4096, 4096, 1024, id & 31, id >> 5, tid, t);
    return;
  }
  id -= 4096;
  if (id < 192) {                        // x_proj^T: grid (64,3)
    transpose_tile(x_proj, Wxp, 2048, 96, 96, 2048, id % 64, id / 64, tid, t);
    return;
  }
  id -= 192;                             // dt_proj^T: grid (2,64)
  transpose_tile(dt_proj, dtw, 64, 2048, 2048, 64, id & 1, id >> 1, tid, t);
}

// ---------------------------------------------------------------------------
// 256x256-tile bf16 MFMA GEMM with cross-tile load/compute overlap.
// C[M x N] = A[M x K] * Bt[N x K]^T.  BK=64, 512 threads = 8 waves (2m x 4n),
// per-wave output 128x64 (8x4 fragments of 16x16x32).  128 KiB LDS,
// double-buffered, T2 granule swizzle (pre-swizzled source col + swizzled
// read col, rule #21).  Per K-tile: 4 phases, each {issue 1/4 of NEXT tile's
// global_load_lds || ds_read A-frags || 16 MFMA (setprio)}; ONE
// vmcnt(0)+lgkmcnt(0) drain + raw s_barrier per tile (loads fly under ~3.5
// phases of MFMA).  Sync: every wave drains its own staging before the
// barrier; a buffer is overwritten only one full iteration after its last
// read; asm "memory" clobber + sched_barrier(0) pin cross-barrier order.
// Requires: M%256==0, N%256==0, K%64==0, full rows in A/Bt (true here).
// mode 5: col<DI -> bf16 token-major Cv (ldc); col>=DI -> Cv2 (ldc2)  [GEMM1]
// mode 2: f32 token-major store                                        [GEMM4]
// ---------------------------------------------------------------------------
__global__ __launch_bounds__(512, 2)
void gemm256(const short* __restrict__ A, const short* __restrict__ Bt,
             void* __restrict__ Cv, void* __restrict__ Cv2,
             int N, int K, int lda, int ldb, int ldc, int ldc2, int mode)
{
  __shared__ short As[2][256][64];     // 64 KiB
  __shared__ short Bs[2][256][64];     // 64 KiB
  // ---- XCD chunk + group-M (GM=4) ----
  const int gx = gridDim.x, gy = gridDim.y;
  const int nwg = gx * gy;
  const int lid = blockIdx.x + gx * blockIdx.y;
  const int cpx = nwg >> 3;                       // nwg % 8 == 0
  const int swz = (lid & 7) * cpx + (lid >> 3);
  const int nig = gy << 2;                        // GM(4) * gy
  const int grp_ = swz / nig;
  const int ing = swz - grp_ * nig;
  const int m0 = (grp_ * 4 + (ing & 3)) * 256;
  const int n0 = (ing >> 2) * 256;

  const int tid  = threadIdx.x;
  const int wid  = tid >> 6, lane = tid & 63;
  const int wm = wid >> 2, wn = wid & 3;          // 2 x 4 wave grid
  const int la = lane & 15, gq = lane >> 4;
  const int rowA0 = wm * 128 + la;
  const int rowB0 = wn * 64 + la;
  const int rs = (la & 7) << 3;                   // read-side XOR
  f32x4 acc[8][4] = {};

  // issue one quarter of a tile's staging: A-chunk Lq + B-chunk Lq (2 loads)
  auto STAGE1 = [&](int buf, int k0, int Lq) {
    int idx = tid + Lq * 512;                     // 0..2047
    int row = idx >> 3, kc8 = (idx & 7) * 8;      // linear LDS: addr = idx*16B
    int kcs = kc8 ^ ((row & 7) << 3);             // pre-swizzled source col
    GLD16(A  + (size_t)(m0 + row) * lda + k0 + kcs, &As[buf][row][kc8]);
    GLD16(Bt + (size_t)(n0 + row) * ldb + k0 + kcs, &Bs[buf][row][kc8]);
  };

  // ---- prologue: stage tile 0 into buf 0, publish ----
#pragma unroll
  for (int q = 0; q < 4; q++) STAGE1(0, 0, q);
  asm volatile("s_waitcnt vmcnt(0) lgkmcnt(0)" ::: "memory");
  __builtin_amdgcn_s_barrier();
  __builtin_amdgcn_sched_barrier(0);

  const int NT = K >> 6;
  int cur = 0;
  for (int kt = 0; kt < NT; kt++) {
    const int knext = (kt + 1) << 6;
    const bool pf = (kt + 1 < NT);
    // B-frags for this tile (shared across the 4 phases)
    bf16x8 bfr[4][2];
#pragma unroll
    for (int j = 0; j < 4; j++)
#pragma unroll
      for (int ks = 0; ks < 2; ks++)
        bfr[j][ks] = *(const bf16x8*)(&Bs[cur][rowB0 + j * 16][(ks * 32 + gq * 8) ^ rs]);
    // 4 phases: {stage 1/4 of next tile || A-frags for 2 rows || 16 MFMA}
#pragma unroll
    for (int q = 0; q < 4; q++) {
      if (pf) STAGE1(cur ^ 1, knext, q);
      bf16x8 af[2][2];
#pragma unroll
      for (int r = 0; r < 2; r++)
#pragma unroll
        for (int ks = 0; ks < 2; ks++)
          af[r][ks] = *(const bf16x8*)(&As[cur][rowA0 + (2 * q + r) * 16][(ks * 32 + gq * 8) ^ rs]);
      __builtin_amdgcn_s_setprio(1);
#pragma unroll
      for (int r = 0; r < 2; r++)
#pragma unroll
        for (int j = 0; j < 4; j++) {
          acc[2 * q + r][j] = __builtin_amdgcn_mfma_f32_16x16x32_bf16(af[r][0], bfr[j][0], acc[2 * q + r][j], 0, 0, 0);
          acc[2 * q + r][j] = __builtin_amdgcn_mfma_f32_16x16x32_bf16(af[r][1], bfr[j][1], acc[2 * q + r][j], 0, 0, 0);
        }
      __builtin_amdgcn_s_setprio(0);
    }
    // drain own staging, publish next buffer, block cross-barrier motion
    asm volatile("s_waitcnt vmcnt(0) lgkmcnt(0)" ::: "memory");
    __builtin_amdgcn_s_barrier();
    __builtin_amdgcn_sched_barrier(0);
    cur ^= 1;
  }

  // ---- epilogue ----
#pragma unroll
  for (int i = 0; i < 8; i++) {
    int rowb = m0 + wm * 128 + i * 16 + gq * 4;
#pragma unroll
    for (int j = 0; j < 4; j++) {
      int col = n0 + wn * 64 + j * 16 + la;
      if (mode == 2) {
#pragma unroll
        for (int r = 0; r < 4; r++)
          ((float*)Cv)[(size_t)(rowb + r) * ldc + col] = acc[i][j][r];
      } else {   // mode 5: split x/res halves, bf16 token-major
        short* base = (col < DI) ? (short*)Cv : (short*)Cv2;
        int c = (col < DI) ? col : col - DI;
        int ld = (col < DI) ? ldc : ldc2;
#pragma unroll
        for (int r = 0; r < 4; r++)
          base[(size_t)(rowb + r) * ld + c] = f2bs(acc[i][j][r]);
      }
    }
  }
}

// ---------------------------------------------------------------------------
// 128x128 bf16 MFMA GEMM (m97 structure) for the small GEMMs (2 and 3).
// BK=64, global_load_lds staging, T2 granule swizzle, XCD+group-M mapping.
// mode 4: col<DTR -> bf16 token-major Cv; col>=DTR -> bf16 transposed Cv2
// mode 6: softplus(v + bias[ROW]) -> bf16 row-major store (ldc)
// ---------------------------------------------------------------------------
__global__ __launch_bounds__(256)
void gemm_bt(const short* __restrict__ A, const short* __restrict__ Bt,
             void* __restrict__ Cv, void* __restrict__ Cv2, const float* __restrict__ bias,
             int N, int K, int lda, int ldb, int ldc, int ldc2, int mode)
{
  __shared__ short As[128][64];
  __shared__ short Bs[128][64];
  const int gx = gridDim.x, gy = gridDim.y;
  const int nwg = gx * gy;
  const int lid = blockIdx.x + gx * blockIdx.y;
  const int cpx = nwg >> 3;
  const int swz = (lid & 7) * cpx + (lid >> 3);
  const int nig = gy << 3;
  const int grp_ = swz / nig;
  const int ing = swz - grp_ * nig;
  const int m0 = (grp_ * 8 + (ing & 7)) * 128;
  const int n0 = (ing >> 3) * 128;
  const int tid  = threadIdx.x;
  const int wave = tid >> 6, lane = tid & 63;
  const int wr = (wave >> 1) * 64, wc = (wave & 1) * 64;
  const int la = lane & 15, gq = lane >> 4;
  const int rs = (la & 7) << 3;
  f32x4 acc[4][4] = {};

  for (int k0 = 0; k0 < K; k0 += 64) {
#pragma unroll
    for (int i = 0; i < 4; i++) {
      int idx = tid + i * 256;
      int row = idx >> 3, kc = (idx & 7) * 8;
      int kcs = kc ^ ((row & 7) << 3);
      GLD16(A  + (size_t)(m0 + row) * lda + k0 + kcs, &As[row][kc]);
      GLD16(Bt + (size_t)(n0 + row) * ldb + k0 + kcs, &Bs[row][kc]);
    }
    __syncthreads();
#pragma unroll
    for (int kk = 0; kk < 2; kk++) {
      const int cl = (kk * 32 + gq * 8) ^ rs;
      bf16x8 af[4], bfr[4];
#pragma unroll
      for (int i = 0; i < 4; i++) af[i]  = *(const bf16x8*)(&As[wr + i * 16 + la][cl]);
#pragma unroll
      for (int j = 0; j < 4; j++) bfr[j] = *(const bf16x8*)(&Bs[wc + j * 16 + la][cl]);
#pragma unroll
      for (int i = 0; i < 4; i++)
#pragma unroll
        for (int j = 0; j < 4; j++)
          acc[i][j] = __builtin_amdgcn_mfma_f32_16x16x32_bf16(af[i], bfr[j], acc[i][j], 0, 0, 0);
    }
    __syncthreads();
  }

#pragma unroll
  for (int i = 0; i < 4; i++) {
    int rowb = m0 + wr + i * 16 + gq * 4;
#pragma unroll
    for (int j = 0; j < 4; j++) {
      int col = n0 + wc + j * 16 + la;
      if (col >= N) continue;
      if (mode == 4) {
        if (col < DTR) {
#pragma unroll
          for (int r = 0; r < 4; r++)
            ((short*)Cv)[(size_t)(rowb + r) * ldc + col] = f2bs(acc[i][j][r]);
        } else {
          s16x4 pk;
#pragma unroll
          for (int r = 0; r < 4; r++) pk[r] = f2bs(acc[i][j][r]);
          *(s16x4*)((short*)Cv2 + (size_t)(col - DTR) * ldc2 + rowb) = pk;
        }
      } else if (mode == 6) {
#pragma unroll
        for (int r = 0; r < 4; r++) {
          float v = acc[i][j][r] + bias[rowb + r];
          float e = exp2f(v * 1.44269504f);
          v = (v > 20.f) ? v : 0.69314718f * __log2f(1.f + e);
          ((short*)Cv)[(size_t)(rowb + r) * ldc + col] = f2bs(v);
        }
      } else { // mode 0: plain bf16 token-major
#pragma unroll
        for (int r = 0; r < 4; r++)
          ((short*)Cv)[(size_t)(rowb + r) * ldc + col] = f2bs(acc[i][j][r]);
      }
    }
  }
}

// ---------------------------------------------------------------------------
// depthwise causal conv1d (k=4) + bias + SiLU (blocks < NTOK), plus
// out_proj^T transpose riding on blocks >= NTOK.
// ---------------------------------------------------------------------------
__global__ __launch_bounds__(256)
void conv_silu(const short* __restrict__ xb, const float* __restrict__ cw,
               const float* __restrict__ cb, short* __restrict__ xs,
               const float* __restrict__ op, short* __restrict__ Wt4)
{
  __shared__ short t[32][33];
  const int blk = blockIdx.x;
  if (blk >= NTOK) {                     // out_proj^T: 2048 blocks, grid (64,32)
    const int id2 = blk - NTOK;
    transpose_tile(op, Wt4, 2048, 1024, 1024, 2048, id2 & 63, id2 >> 6, threadIdx.x, t);
    return;
  }
  const int token = blk;
  const int l = token & (L_ - 1);
  const int d0 = threadIdx.x * 8;

  float w[32];
#pragma unroll
  for (int i = 0; i < 8; i++) {
    float4 tw = *(const float4*)(cw + (size_t)(d0 + i) * 4);
    w[i * 4 + 0] = tw.x; w[i * 4 + 1] = tw.y; w[i * 4 + 2] = tw.z; w[i * 4 + 3] = tw.w;
  }
  float acc[8];
  {
    float4 b0 = *(const float4*)(cb + d0);
    float4 b1 = *(const float4*)(cb + d0 + 4);
    acc[0] = b0.x; acc[1] = b0.y; acc[2] = b0.z; acc[3] = b0.w;
    acc[4] = b1.x; acc[5] = b1.y; acc[6] = b1.z; acc[7] = b1.w;
  }
#pragma unroll
  for (int j = 0; j < 4; j++) {
    int lj = l - 3 + j;
    if (lj >= 0) {
      bf16x8 xv = *(const bf16x8*)(xb + (size_t)(token - 3 + j) * DI + d0);
#pragma unroll
      for (int i = 0; i < 8; i++) acc[i] += w[i * 4 + j] * bf2f(xv[i]);
    }
  }
  union { bf16x8 v; short h[8]; } o;
#pragma unroll
  for (int i = 0; i < 8; i++) {
    float v = acc[i];
    o.h[i] = f2bs(v * sigmoidf_fast(v));
  }
  *(bf16x8*)(xs + (size_t)token * DI + d0) = o.v;
}

// ---------------------------------------------------------------------------
// selective scan, 16 lanes per (b,d) channel (one per state n), fused gating.
// R9-proven: 512-thr blocks (full 64B lines on u/res/y), 2-deep ping-pong,
// setprio around compute, 56 VGPR, no scratch.  220 us floor.
// ---------------------------------------------------------------------------
__global__ __launch_bounds__(512, 1)
void scan_kernel(const short* __restrict__ dT, const short* __restrict__ dbcT,
                 const short* __restrict__ xs, short* __restrict__ resy,
                 const float* __restrict__ A_log, const float* __restrict__ Dw,
                 const float* __restrict__ h0)
{
  const int lane = threadIdx.x & 63;
  const int grp = threadIdx.x >> 4, n = threadIdx.x & 15;
  const int ch = blockIdx.x * 32 + grp;          // ch = b*DI + d  (32 groups/block)
  const int b = ch >> 11, d = ch & (DI - 1);
  const bool b3 = (lane & 8) != 0, b2 = (lane & 4) != 0,
             b1 = (lane & 2) != 0, b0 = (lane & 1) != 0;
  const float An2 = -__expf(A_log[d * NST + n]) * 1.44269504f;  // An * log2(e)
  const float Dd = Dw[d];
  float h = h0[(size_t)ch * NST + n];

  const size_t t0 = (size_t)b * L_;
  const short* dRow = dT   + (size_t)d * NTOK + t0;
  const short* bRow = dbcT + (size_t)n * NTOK + t0;
  const short* cRow = bRow + (size_t)NST * NTOK;
  const short* uLn  = xs   + (t0 + n) * DI + d;  // per-lane u row (lane n = step lv+n)
  short*       yCol = resy + (t0 + n) * DI + d;  // res read / y write, per-lane row

  auto LOADB = [&](int lv, bf16x8& t0v, bf16x8& t1v, bf16x8& B0v, bf16x8& B1v,
                   bf16x8& C0v, bf16x8& C1v, short& uo, short& rr) {
    t0v = *(const bf16x8*)(dRow + lv);
    t1v = *(const bf16x8*)(dRow + lv + 8);
    B0v = *(const bf16x8*)(bRow + lv);
    B1v = *(const bf16x8*)(bRow + lv + 8);
    C0v = *(const bf16x8*)(cRow + lv);
    C1v = *(const bf16x8*)(cRow + lv + 8);
    uo = uLn[(size_t)lv * DI];                   // u[lv+n][d], one load per lane
    rr = yCol[(size_t)lv * DI];
  };

  auto STEP = [&](int lv, bf16x8 t0v, bf16x8 t1v, bf16x8 B0v, bf16x8 B1v,
                  bf16x8 C0v, bf16x8 C1v, short uo, short rr) {
    const float uown = bf2f(uo);
    __builtin_amdgcn_s_setprio(1);
    // ---- broadcast u[s] to all lanes of the group (LDS-pipe, no VMEM) ----
    float uf[16];
    uf[0]  = swz_bcast16<0>(uown);   uf[1]  = swz_bcast16<1>(uown);
    uf[2]  = swz_bcast16<2>(uown);   uf[3]  = swz_bcast16<3>(uown);
    uf[4]  = swz_bcast16<4>(uown);   uf[5]  = swz_bcast16<5>(uown);
    uf[6]  = swz_bcast16<6>(uown);   uf[7]  = swz_bcast16<7>(uown);
    uf[8]  = swz_bcast16<8>(uown);   uf[9]  = swz_bcast16<9>(uown);
    uf[10] = swz_bcast16<10>(uown);  uf[11] = swz_bcast16<11>(uown);
    uf[12] = swz_bcast16<12>(uown);  uf[13] = swz_bcast16<13>(uown);
    uf[14] = swz_bcast16<14>(uown);  uf[15] = swz_bcast16<15>(uown);
    // ---- precompute (independent of h) ----
    float dA[16], w[16];
#pragma unroll
    for (int s = 0; s < 16; s++) {
      float dt = bf2f(s < 8 ? t0v[s] : t1v[s - 8]);
      dA[s] = exp2f(dt * An2);
      w[s]  = dt * uf[s] * bf2f(s < 8 ? B0v[s] : B1v[s - 8]);
    }
    // ---- serial chain (16 FMAs) + per-state output term ----
    float p[16];
#pragma unroll
    for (int s = 0; s < 16; s++) {
      h = __builtin_fmaf(dA[s], h, w[s]);
      p[s] = h * bf2f(s < 8 ? C0v[s] : C1v[s - 8]);
    }
    // ---- butterfly transpose-reduce: lane n -> sum over states of p[n] ----
    float q8[8];
#pragma unroll
    for (int i = 0; i < 8; i++) {
      float keep = b3 ? p[i + 8] : p[i];
      float send = b3 ? p[i]     : p[i + 8];
      q8[i] = keep + swz_xor8(send);
    }
    float q4[4];
#pragma unroll
    for (int i = 0; i < 4; i++) {
      float keep = b2 ? q8[i + 4] : q8[i];
      float send = b2 ? q8[i]     : q8[i + 4];
      q4[i] = keep + swz_xor4(send);
    }
    float q2[2];
#pragma unroll
    for (int i = 0; i < 2; i++) {
      float keep = b1 ? q4[i + 2] : q4[i];
      float send = b1 ? q4[i]     : q4[i + 2];
      q2[i] = keep + qperm<0x4E>(send);       // quad_perm [2,3,0,1] = xor 2
    }
    float keep = b0 ? q2[1] : q2[0];
    float send = b0 ? q2[0] : q2[1];
    float ysum = keep + qperm<0xB1>(send);     // quad_perm [1,0,3,2] = xor 1
    // ---- skip term + gate (lane n owns step lv+n; uown = u[lv+n]) ----
    ysum = __builtin_fmaf(uown, Dd, ysum);
    float r = bf2f(rr);
    float yv = ysum * (r * sigmoidf_fast(r));
    __builtin_amdgcn_s_setprio(0);
    yCol[(size_t)lv * DI] = f2bs(yv);
  };

  bf16x8 a0, a1, a2, a3, a4, a5; short ua, ra;
  bf16x8 c0, c1, c2, c3, c4, c5; short ub, rb;
  LOADB(0, a0, a1, a2, a3, a4, a5, ua, ra);
  for (int l = 0; l < L_; l += 32) {
    LOADB(l + 16, c0, c1, c2, c3, c4, c5, ub, rb);
    STEP(l, a0, a1, a2, a3, a4, a5, ua, ra);
    if (l + 32 < L_) LOADB(l + 32, a0, a1, a2, a3, a4, a5, ua, ra);
    STEP(l + 16, c0, c1, c2, c3, c4, c5, ub, rb);
  }
}

// ---------------------------------------------------------------------------
extern "C" void kernel_launch(void* const* d_in, const int* in_sizes, int n_in,
                              void* d_out, int out_size, void* d_ws, size_t ws_size,
                              hipStream_t stream)
{
  const float* u        = (const float*)d_in[0];
  const float* hiddens  = (const float*)d_in[1];
  const float* in_proj  = (const float*)d_in[2];
  const float* conv_w   = (const float*)d_in[3];
  const float* conv_b   = (const float*)d_in[4];
  const float* x_proj   = (const float*)d_in[5];   // (2048, 96)
  const float* dt_proj  = (const float*)d_in[6];   // (64, 2048)
  const float* dt_bias  = (const float*)d_in[7];
  const float* A_log    = (const float*)d_in[8];
  const float* Dw       = (const float*)d_in[9];
  const float* out_proj = (const float*)d_in[10];
  float* out = (float*)d_out;

  // workspace: ~74 MiB (under the previously proven 78 MiB)
  char* w = (char*)d_ws;
  short* Wt1  = (short*)w;                                 // in_proj^T (4096x1024), 8 MiB
  short* Wt4  = Wt1;                                       // out_proj^T reuses Wt1 after GEMM1
  w += (size_t)4096 * 1024 * 2;
  short* Wxp  = (short*)w; w += (size_t)128  * 2048 * 2;   // x_proj^T, padded to 128 rows
  short* dtw  = (short*)w; w += (size_t)2048 * 64   * 2;   // dt_proj^T  (2048 x 64)
  short* xbuf = (short*)w; w += (size_t)NTOK * DI   * 2;   // x (token-major) -> dT (chan-major)
  short* resy = (short*)w; w += (size_t)NTOK * DI   * 2;   // res (token-major) -> y in-place
  short* dbc  = (short*)w; w += (size_t)NTOK * DTR  * 2;   // dt_rank part, token-major (8192x64)
  short* dbcT = (short*)w; w += (size_t)32   * NTOK * 2;   // B|C transposed (32 x 8192)
  short* ub   = (short*)d_out;                             // u in bf16 (16 MiB, dead after GEMM1)
  short* xs   = (short*)d_out;                             // conv out borrows d_out after GEMM1
  short* dT   = xbuf;                                      // delta^T overlays dead x

  // prep: u->bf16 + in_proj^T + x_proj^T + dt_proj^T in ONE dispatch
  prep<<<4096 + 4096 + 192 + 128, 256, 0, stream>>>(u, ub, in_proj, Wt1,
                                                    x_proj, Wxp, dt_proj, dtw);

  // GEMM1 (256^2 overlapped): [x | res] = ub @ in_proj -> xbuf / resy
  gemm256<<<dim3(32, 16), 512, 0, stream>>>(ub, Wt1, xbuf, resy,
                                            4096, 1024, 1024, 1024, DI, DI, 5);
  // conv + silu -> xs (token-major, in d_out) + out_proj^T -> Wt4 (rides along)
  conv_silu<<<NTOK + 2048, 256, 0, stream>>>(xbuf, conv_w, conv_b, xs, out_proj, Wt4);
  // GEMM2: dbc = xs @ x_proj; dt-rank cols token-major, B/C cols transposed to dbcT
  gemm_bt<<<dim3(64, 1), 256, 0, stream>>>(xs, Wxp, dbc, dbcT, nullptr,
                                           96, 2048, 2048, 2048, DTR, NTOK, 4);
  // GEMM3 (swapped operands): dT[d][t] = softplus(dtw[d,:] . dbc[t,:] + bias[d])
  gemm_bt<<<dim3(16, 64), 256, 0, stream>>>(dtw, dbc, dT, nullptr, dt_bias,
                                            NTOK, 64, 64, 64, NTOK, 0, 6);
  // selective scan + gated epilogue: y overwrites res in-place (token-major)
  scan_kernel<<<256, 512, 0, stream>>>(dT, dbcT, xs, resy, A_log, Dw, hiddens);
  // GEMM4 (256^2 overlapped): out = y @ out_proj  (8192 x 1024, f32 store)
  gemm256<<<dim3(32, 4), 512, 0, stream>>>(resy, Wt4, out, nullptr,
                                           1024, 2048, 2048, 2048, 1024, 0, 2);
}

// Round 11
// 592.987 us; speedup vs baseline: 1.0358x; 1.0358x over previous
//
#include <hip/hip_runtime.h>
#include <hip/hip_bf16.h>
#include <cstddef>

#define B_   4
#define L_   2048
#define DM   1024
#define DI   2048
#define NST  16
#define DTR  64        // (1024+15)//16 = 64
#define NBC  96        // DTR + 2*NST
#define NTOK 8192      // B_*L_

using bf16 = __hip_bfloat16;
typedef __attribute__((ext_vector_type(8))) short bf16x8;
typedef __attribute__((ext_vector_type(4))) short s16x4;
typedef __attribute__((ext_vector_type(4))) float f32x4;

__device__ __forceinline__ float bf2f(short s) {
  unsigned u = ((unsigned)(unsigned short)s) << 16;
  float f; __builtin_memcpy(&f, &u, 4); return f;
}
__device__ __forceinline__ short f2bs(float f) {
  __hip_bfloat16 h = __float2bfloat16(f);
  short s; __builtin_memcpy(&s, &h, 2); return s;
}
__device__ __forceinline__ float sigmoidf_fast(float x) {
  return 1.f / (1.f + __expf(-x));
}

// async global->LDS, 16B per lane (dest must be wave-uniform base + lane*16)
#define GLD16(g, l) __builtin_amdgcn_global_load_lds( \
  (const __attribute__((address_space(1))) unsigned int*)(g), \
  (__attribute__((address_space(3))) unsigned int*)(l), 16, 0, 0)

// cross-lane xor shuffles for the 16-state butterfly reduce (within 32-lane halves)
__device__ __forceinline__ float swz_xor8(float x) {
  return __builtin_bit_cast(float,
    __builtin_amdgcn_ds_swizzle(__builtin_bit_cast(int, x), 0x201F)); // lane ^= 8
}
__device__ __forceinline__ float swz_xor4(float x) {
  return __builtin_bit_cast(float,
    __builtin_amdgcn_ds_swizzle(__builtin_bit_cast(int, x), 0x101F)); // lane ^= 4
}
template<int CTRL>
__device__ __forceinline__ float qperm(float x) {  // DPP quad_perm, full VALU rate
  return __builtin_bit_cast(float,
    __builtin_amdgcn_update_dpp(0, __builtin_bit_cast(int, x), CTRL, 0xf, 0xf, false));
}
// broadcast lane (group_base | S) to all 16 lanes of the group
template<int S>
__device__ __forceinline__ float swz_bcast16(float x) {
  return __builtin_bit_cast(float,
    __builtin_amdgcn_ds_swizzle(__builtin_bit_cast(int, x), (S << 5) | 0x10));
}

// ---------------------------------------------------------------------------
// shared transpose tile helper (f32 -> bf16, zero-pad)
// ---------------------------------------------------------------------------
__device__ __forceinline__ void transpose_tile(
    const float* __restrict__ in, short* __restrict__ out,
    int R, int Cc, int lin, int lout, int bx, int by, int tid, short (*t)[33])
{
  const int r0 = bx * 32, c0 = by * 32;
  const int tx = tid & 31, ty = tid >> 5;
#pragma unroll
  for (int i = 0; i < 4; i++) {
    int r = r0 + ty + i * 8;
    int c = c0 + tx;
    short v = 0;
    if (r < R && c < Cc) v = f2bs(in[(size_t)r * lin + c]);
    t[ty + i * 8][tx] = v;
  }
  __syncthreads();
#pragma unroll
  for (int i = 0; i < 4; i++) {
    int c = c0 + ty + i * 8;
    int r = r0 + tx;
    if (c < Cc && r < lout) out[(size_t)c * lout + r] = t[tx][ty + i * 8];
  }
}

// ---------------------------------------------------------------------------
// prep: one dispatch doing (a) u f32->bf16 convert, (b) in_proj^T,
// (c) x_proj^T, (d) dt_proj^T.  Linear block id -> region.
// ---------------------------------------------------------------------------
__global__ __launch_bounds__(256)
void prep(const float* __restrict__ u, short* __restrict__ ub,
          const float* __restrict__ in_proj, short* __restrict__ Wt1,
          const float* __restrict__ x_proj, short* __restrict__ Wxp,
          const float* __restrict__ dt_proj, short* __restrict__ dtw)
{
  __shared__ short t[32][33];
  int id = blockIdx.x;
  const int tid = threadIdx.x;
  if (id < 4096) {                       // u convert: 4096 blocks x 256 thr x 8
    const size_t i = ((size_t)id * 256 + tid) * 8;
    float4 a0 = *(const float4*)(u + i);
    float4 a1 = *(const float4*)(u + i + 4);
    union { bf16x8 v; short h[8]; } o;
    o.h[0] = f2bs(a0.x); o.h[1] = f2bs(a0.y); o.h[2] = f2bs(a0.z); o.h[3] = f2bs(a0.w);
    o.h[4] = f2bs(a1.x); o.h[5] = f2bs(a1.y); o.h[6] = f2bs(a1.z); o.h[7] = f2bs(a1.w);
    *(bf16x8*)(ub + i) = o.v;
    return;
  }
  id -= 4096;
  if (id < 4096) {                       // in_proj^T: grid (32,128)
    transpose_tile(in_proj, Wt1, 1024, 4096, 4096, 1024, id & 31, id >> 5, tid, t);
    return;
  }
  id -= 4096;
  if (id < 192) {                        // x_proj^T: grid (64,3)
    transpose_tile(x_proj, Wxp, 2048, 96, 96, 2048, id % 64, id / 64, tid, t);
    return;
  }
  id -= 192;                             // dt_proj^T: grid (2,64)
  transpose_tile(dt_proj, dtw, 64, 2048, 2048, 64, id & 1, id >> 1, tid, t);
}

// ---------------------------------------------------------------------------
// bf16 MFMA GEMM, C[M x N] = A[M x K] * Bt[N x K]^T.  128x128 tile, BK=64,
// 4 waves each 64x64 (4x4 of 16x16x32 MFMA).  global_load_lds (16B) staging,
// linear LDS dest with XOR-swizzled SOURCE col (T2 per rule #21).
// Block mapping: XCD chunk (bijective, i%8 -> XCD) THEN group-M swizzle
// (GM=8).  Requires nwg % 8 == 0 and gx % 8 == 0 (all call sites).
// mode 2: f32 token-major store.
// mode 4: col<DTR -> bf16 token-major to Cv (ldc); col>=DTR -> bf16 transposed to Cv2 (ldc2)
// mode 5: col<DI  -> bf16 token-major to Cv (ldc); col>=DI  -> token-major to Cv2 (ldc2)
// mode 6: softplus(v + bias[ROW]) -> bf16 row-major store (ldc)  [GEMM3 swapped form]
// ---------------------------------------------------------------------------
__global__ __launch_bounds__(256)
void gemm_bt(const short* __restrict__ A, const short* __restrict__ Bt,
             void* __restrict__ Cv, void* __restrict__ Cv2, const float* __restrict__ bias,
             int N, int K, int lda, int ldb, int ldc, int ldc2, int mode)
{
  __shared__ short As[128][64];
  __shared__ short Bs[128][64];
  const int gx = gridDim.x, gy = gridDim.y;
  const int nwg = gx * gy;
  const int lid = blockIdx.x + gx * blockIdx.y;
  const int cpx = nwg >> 3;                       // nwg % 8 == 0 for all call sites
  const int swz = (lid & 7) * cpx + (lid >> 3);   // XCD k owns swz in [k*cpx,(k+1)*cpx)
  const int nig = gy << 3;                        // tiles per m-group = GM(8) * gy
  const int grp_ = swz / nig;
  const int ing = swz - grp_ * nig;
  const int m0 = (grp_ * 8 + (ing & 7)) * 128;    // mt fastest within group of 8
  const int n0 = (ing >> 3) * 128;
  const int tid  = threadIdx.x;
  const int wave = tid >> 6, lane = tid & 63;
  const int wr = (wave >> 1) * 64, wc = (wave & 1) * 64;
  const int la = lane & 15, gq = lane >> 4;
  const int rs = (la & 7) << 3;                   // read-side XOR (row&7 == la&7)
  f32x4 acc[4][4] = {};

  for (int k0 = 0; k0 < K; k0 += 64) {
#pragma unroll
    for (int i = 0; i < 4; i++) {
      int idx = tid + i * 256;                    // 0..1023
      int row = idx >> 3, kc = (idx & 7) * 8;     // linear: addr = idx*16B
      int kcs = kc ^ ((row & 7) << 3);            // pre-swizzled global source col
      GLD16(A  + (size_t)(m0 + row) * lda + k0 + kcs, &As[row][kc]);
      GLD16(Bt + (size_t)(n0 + row) * ldb + k0 + kcs, &Bs[row][kc]);
    }
    __syncthreads();
#pragma unroll
    for (int kk = 0; kk < 2; kk++) {
      const int cl = (kk * 32 + gq * 8) ^ rs;     // swizzled read col
      bf16x8 af[4], bfr[4];
#pragma unroll
      for (int i = 0; i < 4; i++) af[i]  = *(const bf16x8*)(&As[wr + i * 16 + la][cl]);
#pragma unroll
      for (int j = 0; j < 4; j++) bfr[j] = *(const bf16x8*)(&Bs[wc + j * 16 + la][cl]);
#pragma unroll
      for (int i = 0; i < 4; i++)
#pragma unroll
        for (int j = 0; j < 4; j++)
          acc[i][j] = __builtin_amdgcn_mfma_f32_16x16x32_bf16(af[i], bfr[j], acc[i][j], 0, 0, 0);
    }
    __syncthreads();
  }

#pragma unroll
  for (int i = 0; i < 4; i++) {
    int rowb = m0 + wr + i * 16 + gq * 4;
#pragma unroll
    for (int j = 0; j < 4; j++) {
      int col = n0 + wc + j * 16 + la;
      if (col >= N) continue;
      if (mode == 2) {
#pragma unroll
        for (int r = 0; r < 4; r++)
          ((float*)Cv)[(size_t)(rowb + r) * ldc + col] = acc[i][j][r];
      } else if (mode == 4) {
        if (col < DTR) {
#pragma unroll
          for (int r = 0; r < 4; r++)
            ((short*)Cv)[(size_t)(rowb + r) * ldc + col] = f2bs(acc[i][j][r]);
        } else {
          s16x4 pk;
#pragma unroll
          for (int r = 0; r < 4; r++) pk[r] = f2bs(acc[i][j][r]);
          *(s16x4*)((short*)Cv2 + (size_t)(col - DTR) * ldc2 + rowb) = pk;
        }
      } else if (mode == 5) {
        short* base = (col < DI) ? (short*)Cv : (short*)Cv2;
        int c = (col < DI) ? col : col - DI;
        int ld = (col < DI) ? ldc : ldc2;
#pragma unroll
        for (int r = 0; r < 4; r++)
          base[(size_t)(rowb + r) * ld + c] = f2bs(acc[i][j][r]);
      } else if (mode == 6) {
        // softplus + per-ROW bias, row-major bf16 store (col = t is lane-consecutive)
#pragma unroll
        for (int r = 0; r < 4; r++) {
          float v = acc[i][j][r] + bias[rowb + r];
          float e = exp2f(v * 1.44269504f);
          v = (v > 20.f) ? v : 0.69314718f * __log2f(1.f + e);
          ((short*)Cv)[(size_t)(rowb + r) * ldc + col] = f2bs(v);
        }
      } else { // mode 0: plain bf16 token-major
#pragma unroll
        for (int r = 0; r < 4; r++)
          ((short*)Cv)[(size_t)(rowb + r) * ldc + col] = f2bs(acc[i][j][r]);
      }
    }
  }
}

// ---------------------------------------------------------------------------
// depthwise causal conv1d (k=4) + bias + SiLU (blocks < NTOK), plus
// out_proj^T transpose riding on blocks >= NTOK.
// ---------------------------------------------------------------------------
__global__ __launch_bounds__(256)
void conv_silu(const short* __restrict__ xb, const float* __restrict__ cw,
               const float* __restrict__ cb, short* __restrict__ xs,
               const float* __restrict__ op, short* __restrict__ Wt4)
{
  __shared__ short t[32][33];
  const int blk = blockIdx.x;
  if (blk >= NTOK) {                     // out_proj^T: 2048 blocks, grid (64,32)
    const int id2 = blk - NTOK;
    transpose_tile(op, Wt4, 2048, 1024, 1024, 2048, id2 & 63, id2 >> 6, threadIdx.x, t);
    return;
  }
  const int token = blk;
  const int l = token & (L_ - 1);
  const int d0 = threadIdx.x * 8;

  float w[32];
#pragma unroll
  for (int i = 0; i < 8; i++) {
    float4 tw = *(const float4*)(cw + (size_t)(d0 + i) * 4);
    w[i * 4 + 0] = tw.x; w[i * 4 + 1] = tw.y; w[i * 4 + 2] = tw.z; w[i * 4 + 3] = tw.w;
  }
  float acc[8];
  {
    float4 b0 = *(const float4*)(cb + d0);
    float4 b1 = *(const float4*)(cb + d0 + 4);
    acc[0] = b0.x; acc[1] = b0.y; acc[2] = b0.z; acc[3] = b0.w;
    acc[4] = b1.x; acc[5] = b1.y; acc[6] = b1.z; acc[7] = b1.w;
  }
#pragma unroll
  for (int j = 0; j < 4; j++) {
    int lj = l - 3 + j;
    if (lj >= 0) {
      bf16x8 xv = *(const bf16x8*)(xb + (size_t)(token - 3 + j) * DI + d0);
#pragma unroll
      for (int i = 0; i < 8; i++) acc[i] += w[i * 4 + j] * bf2f(xv[i]);
    }
  }
  union { bf16x8 v; short h[8]; } o;
#pragma unroll
  for (int i = 0; i < 8; i++) {
    float v = acc[i];
    o.h[i] = f2bs(v * sigmoidf_fast(v));
  }
  *(bf16x8*)(xs + (size_t)token * DI + d0) = o.v;
}

// ---------------------------------------------------------------------------
// selective scan, 16 lanes per (b,d) channel (one per state n), fused gating.
// R9-proven: 512-thr blocks (full 64B lines on u/res/y), 2-deep ping-pong,
// setprio around compute, 56 VGPR, no scratch.  220 us floor.
// ---------------------------------------------------------------------------
__global__ __launch_bounds__(512, 1)
void scan_kernel(const short* __restrict__ dT, const short* __restrict__ dbcT,
                 const short* __restrict__ xs, short* __restrict__ resy,
                 const float* __restrict__ A_log, const float* __restrict__ Dw,
                 const float* __restrict__ h0)
{
  const int lane = threadIdx.x & 63;
  const int grp = threadIdx.x >> 4, n = threadIdx.x & 15;
  const int ch = blockIdx.x * 32 + grp;          // ch = b*DI + d  (32 groups/block)
  const int b = ch >> 11, d = ch & (DI - 1);
  const bool b3 = (lane & 8) != 0, b2 = (lane & 4) != 0,
             b1 = (lane & 2) != 0, b0 = (lane & 1) != 0;
  const float An2 = -__expf(A_log[d * NST + n]) * 1.44269504f;  // An * log2(e)
  const float Dd = Dw[d];
  float h = h0[(size_t)ch * NST + n];

  const size_t t0 = (size_t)b * L_;
  const short* dRow = dT   + (size_t)d * NTOK + t0;
  const short* bRow = dbcT + (size_t)n * NTOK + t0;
  const short* cRow = bRow + (size_t)NST * NTOK;
  const short* uLn  = xs   + (t0 + n) * DI + d;  // per-lane u row (lane n = step lv+n)
  short*       yCol = resy + (t0 + n) * DI + d;  // res read / y write, per-lane row

  auto LOADB = [&](int lv, bf16x8& t0v, bf16x8& t1v, bf16x8& B0v, bf16x8& B1v,
                   bf16x8& C0v, bf16x8& C1v, short& uo, short& rr) {
    t0v = *(const bf16x8*)(dRow + lv);
    t1v = *(const bf16x8*)(dRow + lv + 8);
    B0v = *(const bf16x8*)(bRow + lv);
    B1v = *(const bf16x8*)(bRow + lv + 8);
    C0v = *(const bf16x8*)(cRow + lv);
    C1v = *(const bf16x8*)(cRow + lv + 8);
    uo = uLn[(size_t)lv * DI];                   // u[lv+n][d], one load per lane
    rr = yCol[(size_t)lv * DI];
  };

  auto STEP = [&](int lv, bf16x8 t0v, bf16x8 t1v, bf16x8 B0v, bf16x8 B1v,
                  bf16x8 C0v, bf16x8 C1v, short uo, short rr) {
    const float uown = bf2f(uo);
    __builtin_amdgcn_s_setprio(1);
    // ---- broadcast u[s] to all lanes of the group (LDS-pipe, no VMEM) ----
    float uf[16];
    uf[0]  = swz_bcast16<0>(uown);   uf[1]  = swz_bcast16<1>(uown);
    uf[2]  = swz_bcast16<2>(uown);   uf[3]  = swz_bcast16<3>(uown);
    uf[4]  = swz_bcast16<4>(uown);   uf[5]  = swz_bcast16<5>(uown);
    uf[6]  = swz_bcast16<6>(uown);   uf[7]  = swz_bcast16<7>(uown);
    uf[8]  = swz_bcast16<8>(uown);   uf[9]  = swz_bcast16<9>(uown);
    uf[10] = swz_bcast16<10>(uown);  uf[11] = swz_bcast16<11>(uown);
    uf[12] = swz_bcast16<12>(uown);  uf[13] = swz_bcast16<13>(uown);
    uf[14] = swz_bcast16<14>(uown);  uf[15] = swz_bcast16<15>(uown);
    // ---- precompute (independent of h) ----
    float dA[16], w[16];
#pragma unroll
    for (int s = 0; s < 16; s++) {
      float dt = bf2f(s < 8 ? t0v[s] : t1v[s - 8]);
      dA[s] = exp2f(dt * An2);
      w[s]  = dt * uf[s] * bf2f(s < 8 ? B0v[s] : B1v[s - 8]);
    }
    // ---- serial chain (16 FMAs) + per-state output term ----
    float p[16];
#pragma unroll
    for (int s = 0; s < 16; s++) {
      h = __builtin_fmaf(dA[s], h, w[s]);
      p[s] = h * bf2f(s < 8 ? C0v[s] : C1v[s - 8]);
    }
    // ---- butterfly transpose-reduce: lane n -> sum over states of p[n] ----
    float q8[8];
#pragma unroll
    for (int i = 0; i < 8; i++) {
      float keep = b3 ? p[i + 8] : p[i];
      float send = b3 ? p[i]     : p[i + 8];
      q8[i] = keep + swz_xor8(send);
    }
    float q4[4];
#pragma unroll
    for (int i = 0; i < 4; i++) {
      float keep = b2 ? q8[i + 4] : q8[i];
      float send = b2 ? q8[i]     : q8[i + 4];
      q4[i] = keep + swz_xor4(send);
    }
    float q2[2];
#pragma unroll
    for (int i = 0; i < 2; i++) {
      float keep = b1 ? q4[i + 2] : q4[i];
      float send = b1 ? q4[i]     : q4[i + 2];
      q2[i] = keep + qperm<0x4E>(send);       // quad_perm [2,3,0,1] = xor 2
    }
    float keep = b0 ? q2[1] : q2[0];
    float send = b0 ? q2[0] : q2[1];
    float ysum = keep + qperm<0xB1>(send);     // quad_perm [1,0,3,2] = xor 1
    // ---- skip term + gate (lane n owns step lv+n; uown = u[lv+n]) ----
    ysum = __builtin_fmaf(uown, Dd, ysum);
    float r = bf2f(rr);
    float yv = ysum * (r * sigmoidf_fast(r));
    __builtin_amdgcn_s_setprio(0);
    yCol[(size_t)lv * DI] = f2bs(yv);
  };

  bf16x8 a0, a1, a2, a3, a4, a5; short ua, ra;
  bf16x8 c0, c1, c2, c3, c4, c5; short ub, rb;
  LOADB(0, a0, a1, a2, a3, a4, a5, ua, ra);
  for (int l = 0; l < L_; l += 32) {
    LOADB(l + 16, c0, c1, c2, c3, c4, c5, ub, rb);
    STEP(l, a0, a1, a2, a3, a4, a5, ua, ra);
    if (l + 32 < L_) LOADB(l + 32, a0, a1, a2, a3, a4, a5, ua, ra);
    STEP(l + 16, c0, c1, c2, c3, c4, c5, ub, rb);
  }
}

// ---------------------------------------------------------------------------
extern "C" void kernel_launch(void* const* d_in, const int* in_sizes, int n_in,
                              void* d_out, int out_size, void* d_ws, size_t ws_size,
                              hipStream_t stream)
{
  const float* u        = (const float*)d_in[0];
  const float* hiddens  = (const float*)d_in[1];
  const float* in_proj  = (const float*)d_in[2];
  const float* conv_w   = (const float*)d_in[3];
  const float* conv_b   = (const float*)d_in[4];
  const float* x_proj   = (const float*)d_in[5];   // (2048, 96)
  const float* dt_proj  = (const float*)d_in[6];   // (64, 2048)
  const float* dt_bias  = (const float*)d_in[7];
  const float* A_log    = (const float*)d_in[8];
  const float* Dw       = (const float*)d_in[9];
  const float* out_proj = (const float*)d_in[10];
  float* out = (float*)d_out;

  // workspace: ~74 MiB (under the previously proven 78 MiB)
  char* w = (char*)d_ws;
  short* Wt1  = (short*)w;                                 // in_proj^T (4096x1024), 8 MiB
  short* Wt4  = Wt1;                                       // out_proj^T reuses Wt1 after GEMM1
  w += (size_t)4096 * 1024 * 2;
  short* Wxp  = (short*)w; w += (size_t)128  * 2048 * 2;   // x_proj^T, padded to 128 rows
  short* dtw  = (short*)w; w += (size_t)2048 * 64   * 2;   // dt_proj^T  (2048 x 64)
  short* xbuf = (short*)w; w += (size_t)NTOK * DI   * 2;   // x (token-major) -> dT (chan-major)
  short* resy = (short*)w; w += (size_t)NTOK * DI   * 2;   // res (token-major) -> y in-place
  short* dbc  = (short*)w; w += (size_t)NTOK * DTR  * 2;   // dt_rank part, token-major (8192x64)
  short* dbcT = (short*)w; w += (size_t)32   * NTOK * 2;   // B|C transposed (32 x 8192)
  short* ub   = (short*)d_out;                             // u in bf16 (16 MiB, dead after GEMM1)
  short* xs   = (short*)d_out;                             // conv out borrows d_out after GEMM1
  short* dT   = xbuf;                                      // delta^T overlays dead x

  // prep: u->bf16 + in_proj^T + x_proj^T + dt_proj^T in ONE dispatch
  prep<<<4096 + 4096 + 192 + 128, 256, 0, stream>>>(u, ub, in_proj, Wt1,
                                                    x_proj, Wxp, dt_proj, dtw);

  // GEMM1: [x | res] = ub @ in_proj, split into xbuf / resy (token-major, ld=DI)
  gemm_bt<<<dim3(64, 32), 256, 0, stream>>>(ub, Wt1, xbuf, resy, nullptr,
                                            4096, 1024, 1024, 1024, DI, DI, 5);
  // conv + silu -> xs (token-major, in d_out) + out_proj^T -> Wt4 (rides along)
  conv_silu<<<NTOK + 2048, 256, 0, stream>>>(xbuf, conv_w, conv_b, xs, out_proj, Wt4);
  // GEMM2: dbc = xs @ x_proj; dt-rank cols token-major, B/C cols transposed to dbcT
  gemm_bt<<<dim3(64, 1), 256, 0, stream>>>(xs, Wxp, dbc, dbcT, nullptr,
                                           96, 2048, 2048, 2048, DTR, NTOK, 4);
  // GEMM3 (swapped operands): dT[d][t] = softplus(dtw[d,:] . dbc[t,:] + bias[d])
  gemm_bt<<<dim3(16, 64), 256, 0, stream>>>(dtw, dbc, dT, nullptr, dt_bias,
                                            NTOK, 64, 64, 64, NTOK, 0, 6);
  // selective scan + gated epilogue: y overwrites res in-place (token-major)
  scan_kernel<<<256, 512, 0, stream>>>(dT, dbcT, xs, resy, A_log, Dw, hiddens);
  // GEMM4: out = y @ out_proj  (8192 x 1024, f32 store)
  gemm_bt<<<dim3(64, 8), 256, 0, stream>>>(resy, Wt4, out, nullptr, nullptr,
                                           1024, 2048, 2048, 2048, 1024, 0, 2);
}